// Round 1
// baseline (11.779 us; speedup 1.0000x reference)
//
#include <hip/hip_runtime.h>
#include <math.h>

// CenterLoss reduces to: for each row b, d_b = clip(1 - cos(f_b, c_{t_b}), EPS, MAXV);
// loss = mean_b(d_b) + (C-1)*EPS   (the clip floors all masked-out zeros at EPS).

#define BATCH_N 4096
#define EMBED_N 512
#define NUM_CLASSES_N 10000
#define EPS_F 1e-12f
#define MAXV_F 1e12f

// One wave (64 lanes) per batch row; 4 waves per block.
__global__ __launch_bounds__(256) void center_loss_rows(
    const float* __restrict__ features,   // (B, 512)
    const float* __restrict__ centers,    // (C, 512)
    const int*   __restrict__ targets,    // (B,)
    float*       __restrict__ row_out)    // (B,)
{
    const int wave = threadIdx.x >> 6;       // 0..3
    const int lane = threadIdx.x & 63;
    const int b = blockIdx.x * 4 + wave;
    if (b >= BATCH_N) return;

    const int t = targets[b];
    const float4* f4 = (const float4*)(features + (size_t)b * EMBED_N);
    const float4* c4 = (const float4*)(centers  + (size_t)t * EMBED_N);

    float dot = 0.f, ff = 0.f, cc = 0.f;
    // 512 floats = 128 float4; 64 lanes x 2 iters, lane-consecutive (coalesced).
    #pragma unroll
    for (int k = 0; k < 2; ++k) {
        const float4 fv = f4[lane + 64 * k];
        const float4 cv = c4[lane + 64 * k];
        dot += fv.x * cv.x + fv.y * cv.y + fv.z * cv.z + fv.w * cv.w;
        ff  += fv.x * fv.x + fv.y * fv.y + fv.z * fv.z + fv.w * fv.w;
        cc  += cv.x * cv.x + cv.y * cv.y + cv.z * cv.z + cv.w * cv.w;
    }

    // 64-lane butterfly reduction.
    #pragma unroll
    for (int off = 32; off >= 1; off >>= 1) {
        dot += __shfl_xor(dot, off, 64);
        ff  += __shfl_xor(ff,  off, 64);
        cc  += __shfl_xor(cc,  off, 64);
    }

    if (lane == 0) {
        float d = 1.0f - dot / (sqrtf(ff) * sqrtf(cc));
        d = fminf(fmaxf(d, EPS_F), MAXV_F);
        row_out[b] = d;
    }
}

// Deterministic tree reduction of the 4096 per-row values.
__global__ __launch_bounds__(256) void center_loss_reduce(
    const float* __restrict__ row_vals,   // (B,)
    float*       __restrict__ out)        // scalar
{
    __shared__ float sdata[4];
    const int tid = threadIdx.x;

    float s = 0.f;
    #pragma unroll
    for (int k = 0; k < BATCH_N / 256; ++k) s += row_vals[tid + 256 * k];

    #pragma unroll
    for (int off = 32; off >= 1; off >>= 1) s += __shfl_xor(s, off, 64);

    if ((tid & 63) == 0) sdata[tid >> 6] = s;
    __syncthreads();
    if (tid == 0) {
        const float tot = sdata[0] + sdata[1] + sdata[2] + sdata[3];
        // + (B*C - B) * EPS / B  from clip() flooring the masked-out zeros.
        out[0] = tot * (1.0f / BATCH_N)
               + (float)((double)(NUM_CLASSES_N - 1) * 1e-12);
    }
}

extern "C" void kernel_launch(void* const* d_in, const int* in_sizes, int n_in,
                              void* d_out, int out_size, void* d_ws, size_t ws_size,
                              hipStream_t stream) {
    const float* features = (const float*)d_in[0];
    const float* centers  = (const float*)d_in[1];
    const int*   targets  = (const int*)d_in[2];
    float* out = (float*)d_out;
    float* row_vals = (float*)d_ws;   // 4096 floats = 16 KiB scratch

    center_loss_rows<<<BATCH_N / 4, 256, 0, stream>>>(features, centers, targets, row_vals);
    center_loss_reduce<<<1, 256, 0, stream>>>(row_vals, out);
}